// Round 9
// baseline (312.305 us; speedup 1.0000x reference)
//
#include <hip/hip_runtime.h>
#include <hip/hip_bf16.h>
#include <stdint.h>

// ---------------------------------------------------------------------------
// SARoutingBlock. Round 9: attn latency fix — all 16 K loads batched into a
// register array before the QK^T MFMAs (one exposed L2 latency, not 8), and
// all 16 V loads issued before phase 2 so they overlap the softmax VALU work.
// Rest identical to round 8.
// ---------------------------------------------------------------------------

typedef __bf16 bf16x8 __attribute__((ext_vector_type(8)));
typedef float f32x4 __attribute__((ext_vector_type(4)));

#define NEGV -1e9f

__device__ __forceinline__ float b2f(unsigned short h) {
    union { unsigned int u; float f; } x; x.u = ((unsigned int)h) << 16; return x.f;
}
__device__ __forceinline__ unsigned short f2b(float f) {
    union { float f; unsigned int u; } x; x.f = f;
    unsigned int u = x.u + 0x7FFFu + ((x.u >> 16) & 1u);
    return (unsigned short)(u >> 16);
}
__device__ __forceinline__ unsigned int packbf(unsigned int u0, unsigned int u1) {
    unsigned int r0 = (u0 + 0x7FFFu + ((u0 >> 16) & 1u)) >> 16;
    unsigned int r1 = (u1 + 0x7FFFu + ((u1 >> 16) & 1u)) & 0xFFFF0000u;
    return r0 | r1;
}
__device__ __forceinline__ uint4 load8bf(const void* base, size_t elemOff, int isF32) {
    if (!isF32) return *(const uint4*)((const unsigned short*)base + elemOff);
    const uint4* f = (const uint4*)((const float*)base + elemOff);
    uint4 a = f[0], b = f[1];
    uint4 r;
    r.x = packbf(a.x, a.y);
    r.y = packbf(a.z, a.w);
    r.z = packbf(b.x, b.y);
    r.w = packbf(b.z, b.w);
    return r;
}
__device__ __forceinline__ float loadF(const void* p, int idx, int isF32) {
    return isF32 ? ((const float*)p)[idx] : b2f(((const unsigned short*)p)[idx]);
}
__device__ __forceinline__ bf16x8 u2b(uint4 u) {
    union { uint4 a; bf16x8 b; } x; x.a = u; return x.b;
}

// ---------------------------------------------------------------------------
// Sniffer: flags[0]=mask mode (0=i32,1=u8,2=f32,3=bf16); flags[1]=v/k/q dtype
// (0=bf16,1=f32); flags[2]=weights dtype.
// ---------------------------------------------------------------------------
__global__ void sniff_kernel(const unsigned int* __restrict__ mp,
                             const unsigned int* __restrict__ vp,
                             const unsigned int* __restrict__ wp,
                             int* __restrict__ flags)
{
    __shared__ int oki, oku, okf, badv, badw;
    if (threadIdx.x == 0) { oki = 1; oku = 1; okf = 1; badv = 0; badw = 0; }
    __syncthreads();
    int li = 1, lu = 1, lf = 1, bv = 0, bw = 0;
    for (int i = threadIdx.x; i < 16384; i += 256) {
        unsigned int w = mp[i];
        if (w > 1u) li = 0;
        if (w & 0xFEFEFEFEu) lu = 0;
        if (w != 0u && w != 0x3F800000u) lf = 0;
    }
    for (int i = threadIdx.x; i < 8192; i += 256) {
        unsigned int w = vp[i];
        float f0 = b2f((unsigned short)(w & 0xFFFF));
        float f1 = b2f((unsigned short)(w >> 16));
        if (!(fabsf(f0) < 1e4f) || !(fabsf(f1) < 1e4f)) bv = 1;
        w = wp[i];
        f0 = b2f((unsigned short)(w & 0xFFFF));
        f1 = b2f((unsigned short)(w >> 16));
        if (!(fabsf(f0) < 1e4f) || !(fabsf(f1) < 1e4f)) bw = 1;
    }
    if (!li) atomicAnd(&oki, 0);
    if (!lu) atomicAnd(&oku, 0);
    if (!lf) atomicAnd(&okf, 0);
    if (bv) atomicOr(&badv, 1);
    if (bw) atomicOr(&badw, 1);
    __syncthreads();
    if (threadIdx.x == 0) {
        flags[0] = oki ? 0 : (oku ? 1 : (okf ? 2 : 3));
        flags[1] = badv;
        flags[2] = badw;
    }
}

// ---------------------------------------------------------------------------
// conv_act: v,k,q -> contiguous bf16 copies. Grid (1536, 3) x 256 thr, 8/thr.
// ---------------------------------------------------------------------------
__global__ __launch_bounds__(256) void conv_act_kernel(
        const void* __restrict__ v, const void* __restrict__ k,
        const void* __restrict__ q, const int* __restrict__ flags,
        unsigned short* __restrict__ vb, unsigned short* __restrict__ kb,
        unsigned short* __restrict__ qb)
{
    const int dtV = flags[1];
    const int which = blockIdx.y;
    const void* src = (which == 0) ? v : (which == 1) ? k : q;
    unsigned short* dst = (which == 0) ? vb : (which == 1) ? kb : qb;
    size_t off = ((size_t)blockIdx.x * 256 + threadIdx.x) * 8;
    uint4 r = load8bf(src, off, dtV);
    *(uint4*)(dst + off) = r;
}

// ---------------------------------------------------------------------------
// conv_wt: W[768][768] -> WT bf16 [n][k] (transposed). Grid (144, 4), 256 thr.
// ---------------------------------------------------------------------------
__global__ __launch_bounds__(256) void conv_wt_kernel(
        const void* __restrict__ W0, const void* __restrict__ W1,
        const void* __restrict__ W2, const void* __restrict__ W3,
        const int* __restrict__ flags,
        unsigned short* __restrict__ T0, unsigned short* __restrict__ T1,
        unsigned short* __restrict__ T2, unsigned short* __restrict__ T3)
{
    __shared__ unsigned short tile[64][65];
    const int t = threadIdx.x;
    const int dtW = flags[2];
    const int which = blockIdx.y;
    const void* W = (which == 0) ? W0 : (which == 1) ? W1 : (which == 2) ? W2 : W3;
    unsigned short* T = (which == 0) ? T0 : (which == 1) ? T1 : (which == 2) ? T2 : T3;
    const int tk = (blockIdx.x / 12) << 6;
    const int tn = (blockIdx.x % 12) << 6;
    #pragma unroll
    for (int i = 0; i < 16; i++) {
        int idx = (i << 8) + t;
        int r = idx >> 6, c = idx & 63;
        tile[r][c] = f2b(loadF(W, (tk + r) * 768 + tn + c, dtW));
    }
    __syncthreads();
    #pragma unroll
    for (int i = 0; i < 16; i++) {
        int idx = (i << 8) + t;
        int rn = idx >> 6, ck = idx & 63;
        T[(size_t)(tn + rn) * 768 + tk + ck] = tile[ck][rn];
    }
}

// ---------------------------------------------------------------------------
// Mask bit-pack: pm[grow*16 + lm], grow = (l*8+b)*512 + n,
// bit g = mask[l,b,n, g*16+lm]. One block packs 32 rows.
// ---------------------------------------------------------------------------
__global__ __launch_bounds__(256) void pack_kernel(
        const void* __restrict__ masks, const int* __restrict__ flags,
        unsigned int* __restrict__ pm)
{
    __shared__ unsigned char flg[32 * 512];
    const int t = threadIdx.x;
    const int mode = flags[0];
    const size_t e0 = (size_t)blockIdx.x * (32 * 512);
    if (mode == 0 || mode == 2) {
        const uint4* p = (const uint4*)((const unsigned int*)masks + e0);
        for (int i = t; i < 4096; i += 256) {
            uint4 u = p[i];
            int base = i << 2;
            flg[base + 0] = u.x ? 1 : 0;
            flg[base + 1] = u.y ? 1 : 0;
            flg[base + 2] = u.z ? 1 : 0;
            flg[base + 3] = u.w ? 1 : 0;
        }
    } else if (mode == 1) {
        const uint4* p = (const uint4*)((const unsigned char*)masks + e0);
        for (int i = t; i < 1024; i += 256) {
            uint4 u = p[i];
            unsigned int uu[4] = {u.x, u.y, u.z, u.w};
            int base = i << 4;
            #pragma unroll
            for (int k2 = 0; k2 < 4; k2++)
                #pragma unroll
                for (int bb = 0; bb < 4; bb++)
                    flg[base + k2 * 4 + bb] = ((uu[k2] >> (bb * 8)) & 0xFFu) ? 1 : 0;
        }
    } else {
        const uint4* p = (const uint4*)((const unsigned short*)masks + e0);
        for (int i = t; i < 2048; i += 256) {
            uint4 u = p[i];
            unsigned int uu[4] = {u.x, u.y, u.z, u.w};
            int base = i << 3;
            #pragma unroll
            for (int k2 = 0; k2 < 4; k2++) {
                flg[base + k2 * 2 + 0] = (uu[k2] & 0xFFFFu) ? 1 : 0;
                flg[base + k2 * 2 + 1] = (uu[k2] >> 16) ? 1 : 0;
            }
        }
    }
    __syncthreads();
    for (int widx = t; widx < 512; widx += 256) {
        int rl = widx >> 4, lm = widx & 15;
        unsigned int bits = 0;
        #pragma unroll
        for (int g = 0; g < 32; g++)
            bits |= ((unsigned int)(flg[rl * 512 + (g << 4) + lm] & 1)) << g;
        pm[(size_t)blockIdx.x * 512 + widx] = bits;
    }
}

// ---------------------------------------------------------------------------
// Routing stage 1: raw pooling scores per row (64 rows/block, 4 thr/row).
// ---------------------------------------------------------------------------
__global__ __launch_bounds__(256) void route_score_kernel(
        const void* __restrict__ v, const void* __restrict__ pool_w,
        const void* __restrict__ pool_b, const int* __restrict__ flags,
        float* __restrict__ scores)
{
    __shared__ float pw[768];
    const int t = threadIdx.x;
    const int b = blockIdx.x >> 3, ch = blockIdx.x & 7;
    const int dtV = flags[1], dtW = flags[2];
    for (int d = t; d < 768; d += 256) pw[d] = loadF(pool_w, d, dtW);
    __syncthreads();
    const int r = t >> 2, c4 = t & 3;
    const int n = (ch << 6) + r;
    float dot = 0.f, asum = 0.f;
    if (!dtV) {
        const unsigned int* vr = (const unsigned int*)v + ((size_t)(b * 512 + n)) * 384;
        for (int j = 0; j < 96; j++) {
            int p = c4 + (j << 2);
            unsigned int u = vr[p];
            float f0 = b2f((unsigned short)(u & 0xFFFF));
            float f1 = b2f((unsigned short)(u >> 16));
            asum += fabsf(f0) + fabsf(f1);
            dot += f0 * pw[2 * p] + f1 * pw[2 * p + 1];
        }
    } else {
        const float* vf = (const float*)v + ((size_t)(b * 512 + n)) * 768;
        for (int j = 0; j < 48; j++) {
            float4 u = ((const float4*)vf)[c4 + (j << 2)];
            int e = (c4 + (j << 2)) << 2;
            asum += fabsf(u.x) + fabsf(u.y) + fabsf(u.z) + fabsf(u.w);
            dot += u.x * pw[e] + u.y * pw[e + 1] + u.z * pw[e + 2] + u.w * pw[e + 3];
        }
    }
    dot += __shfl_xor(dot, 1); dot += __shfl_xor(dot, 2);
    asum += __shfl_xor(asum, 1); asum += __shfl_xor(asum, 2);
    if (c4 == 0)
        scores[b * 512 + n] = (asum == 0.f) ? NEGV : dot + loadF(pool_b, 0, dtW);
}

// ---------------------------------------------------------------------------
// Routing stage 2: softmax over N per batch -> scs. 8 blocks x 512.
// ---------------------------------------------------------------------------
__global__ __launch_bounds__(512) void route_softmax_kernel(
        const float* __restrict__ scores, float* __restrict__ scs)
{
    __shared__ float red[8];
    const int t = threadIdx.x, b = blockIdx.x;
    float scv = scores[b * 512 + t];
    float mx = scv;
    #pragma unroll
    for (int off = 1; off < 64; off <<= 1) mx = fmaxf(mx, __shfl_xor(mx, off));
    if ((t & 63) == 0) red[t >> 6] = mx;
    __syncthreads();
    float M = red[0];
    #pragma unroll
    for (int i = 1; i < 8; i++) M = fmaxf(M, red[i]);
    float e = __expf(scv - M);
    __syncthreads();
    float sm = e;
    #pragma unroll
    for (int off = 1; off < 64; off <<= 1) sm += __shfl_xor(sm, off);
    if ((t & 63) == 0) red[t >> 6] = sm;
    __syncthreads();
    float SS = 0.f;
    #pragma unroll
    for (int i = 0; i < 8; i++) SS += red[i];
    scs[b * 512 + t] = e / SS;
}

// ---------------------------------------------------------------------------
// Routing stage 3: partial pooled sums. Grid (8 chunks, 8 b), 256 thr.
// ---------------------------------------------------------------------------
__global__ __launch_bounds__(256) void route_pool_kernel(
        const void* __restrict__ v, const int* __restrict__ flags,
        const float* __restrict__ scs, float* __restrict__ ppart)
{
    __shared__ float ps[64];
    const int t = threadIdx.x;
    const int ch = blockIdx.x, b = blockIdx.y;
    const int dtV = flags[1];
    if (t < 64) ps[t] = scs[b * 512 + (ch << 6) + t];
    __syncthreads();
    const int d0 = t * 3;
    float a0 = 0.f, a1 = 0.f, a2 = 0.f;
    if (!dtV) {
        const unsigned short* vb = (const unsigned short*)v
            + ((size_t)(b * 512 + (ch << 6))) * 768 + d0;
        #pragma unroll 4
        for (int r = 0; r < 64; r++) {
            float p = ps[r];
            a0 += b2f(vb[0]) * p; a1 += b2f(vb[1]) * p; a2 += b2f(vb[2]) * p;
            vb += 768;
        }
    } else {
        const float* vb = (const float*)v + ((size_t)(b * 512 + (ch << 6))) * 768 + d0;
        #pragma unroll 4
        for (int r = 0; r < 64; r++) {
            float p = ps[r];
            a0 += vb[0] * p; a1 += vb[1] * p; a2 += vb[2] * p;
            vb += 768;
        }
    }
    float* o = ppart + ((size_t)(b * 8 + ch)) * 768 + d0;
    o[0] = a0; o[1] = a1; o[2] = a2;
}

// ---------------------------------------------------------------------------
// Routing stage 4: hidden units + partial logits. Grid (12 jc, 8 b), 256 thr.
// ---------------------------------------------------------------------------
__global__ __launch_bounds__(256) void route_hid_kernel(
        const void* __restrict__ w1, const void* __restrict__ w2,
        const int* __restrict__ flags, const float* __restrict__ ppart,
        float* __restrict__ plog)
{
    __shared__ float pool[768];
    __shared__ float red[4][32];
    const int t = threadIdx.x;
    const int jc = blockIdx.x, b = blockIdx.y;
    const int dtW = flags[2];
    for (int d = t; d < 768; d += 256) {
        float a = 0.f;
        #pragma unroll
        for (int c = 0; c < 8; c++) a += ppart[((size_t)(b * 8 + c)) * 768 + d];
        pool[d] = a;
    }
    __syncthreads();
    const int jo = (t & 3) << 3;
    const int dr = t >> 2;
    float acc[8];
    #pragma unroll
    for (int j = 0; j < 8; j++) acc[j] = 0.f;
    for (int it = 0; it < 12; it++) {
        int d = (it << 6) + dr;
        float pv = pool[d];
        size_t off = (size_t)d * 384 + (jc << 5) + jo;
        if (!dtW) {
            uint4 u = *(const uint4*)((const unsigned short*)w1 + off);
            unsigned int uu[4] = {u.x, u.y, u.z, u.w};
            #pragma unroll
            for (int j2 = 0; j2 < 4; j2++) {
                acc[2 * j2]     += pv * b2f((unsigned short)(uu[j2] & 0xFFFF));
                acc[2 * j2 + 1] += pv * b2f((unsigned short)(uu[j2] >> 16));
            }
        } else {
            const float4* f = (const float4*)((const float*)w1 + off);
            float4 u0 = f[0], u1 = f[1];
            acc[0] += pv * u0.x; acc[1] += pv * u0.y;
            acc[2] += pv * u0.z; acc[3] += pv * u0.w;
            acc[4] += pv * u1.x; acc[5] += pv * u1.y;
            acc[6] += pv * u1.z; acc[7] += pv * u1.w;
        }
    }
    #pragma unroll
    for (int off = 4; off < 64; off <<= 1)
        #pragma unroll
        for (int j = 0; j < 8; j++) acc[j] += __shfl_xor(acc[j], off);
    const int w = t >> 6, lane = t & 63;
    if (lane < 4) {
        #pragma unroll
        for (int j = 0; j < 8; j++) red[w][lane * 8 + j] = acc[j];
    }
    __syncthreads();
    if (t < 32) {
        float h = red[0][t] + red[1][t] + red[2][t] + red[3][t];
        h = fmaxf(h, 0.f);
        int jg = (jc << 5) + t;
        float l0 = h * loadF(w2, jg * 3 + 0, dtW);
        float l1 = h * loadF(w2, jg * 3 + 1, dtW);
        float l2 = h * loadF(w2, jg * 3 + 2, dtW);
        #pragma unroll
        for (int off = 1; off < 32; off <<= 1) {
            l0 += __shfl_xor(l0, off);
            l1 += __shfl_xor(l1, off);
            l2 += __shfl_xor(l2, off);
        }
        if (t == 0) {
            float* o = plog + ((size_t)(b * 12 + jc)) * 3;
            o[0] = l0; o[1] = l1; o[2] = l2;
        }
    }
}

// ---------------------------------------------------------------------------
// Routing stage 5: reduce partial logits, softmax -> alphas. 8 tiny blocks.
// ---------------------------------------------------------------------------
__global__ __launch_bounds__(64) void route_alpha_kernel(
        const void* __restrict__ b2, const int* __restrict__ flags,
        const float* __restrict__ plog, float* __restrict__ alphas)
{
    const int t = threadIdx.x, b = blockIdx.x;
    if (t == 0) {
        const int dtW = flags[2];
        float lg[3];
        #pragma unroll
        for (int l = 0; l < 3; l++) {
            float a = loadF(b2, l, dtW);
            for (int jc = 0; jc < 12; jc++) a += plog[((size_t)(b * 12 + jc)) * 3 + l];
            lg[l] = a;
        }
        float mm = fmaxf(lg[0], fmaxf(lg[1], lg[2]));
        float e0 = __expf(lg[0] - mm), e1 = __expf(lg[1] - mm), e2 = __expf(lg[2] - mm);
        float ss = e0 + e1 + e2;
        alphas[b * 3 + 0] = e0 / ss;
        alphas[b * 3 + 1] = e1 / ss;
        alphas[b * 3 + 2] = e2 / ss;
    }
}

// ---------------------------------------------------------------------------
// Pipelined MFMA bf16 GEMM, up to 3 sub-gemms selected by blockIdx.y.
// BK=64 (12 steps), register prefetch across the barrier. LDS 16 KB.
// ---------------------------------------------------------------------------
__global__ __launch_bounds__(256) void gemm3_kernel(
        const unsigned short* __restrict__ X0, const unsigned short* __restrict__ X1,
        const unsigned short* __restrict__ X2,
        const unsigned short* __restrict__ W0, const unsigned short* __restrict__ W1,
        const unsigned short* __restrict__ W2,
        const void* __restrict__ bias0, const void* __restrict__ bias1,
        const void* __restrict__ bias2,
        const int* __restrict__ flags,
        void* __restrict__ dst0, void* __restrict__ dst1, void* __restrict__ dst2,
        int m0, int m1, int m2)
{
    __shared__ unsigned short smem[8192];   // At[4096] + Bt[4096], 16 KB
    unsigned short* At = smem;
    unsigned short* Bt = smem + 4096;
    const int t = threadIdx.x;
    const int which = blockIdx.y;
    const unsigned short* X  = (which == 0) ? X0 : (which == 1) ? X1 : X2;
    const unsigned short* WT = (which == 0) ? W0 : (which == 1) ? W1 : W2;
    const void* bias = (which == 0) ? bias0 : (which == 1) ? bias1 : bias2;
    void* dst = (which == 0) ? dst0 : (which == 1) ? dst1 : dst2;
    const int mode = (which == 0) ? m0 : (which == 1) ? m1 : m2;

    const int id = blockIdx.x;
    const int bx = id >> 6, by = id & 63;
    const int row0 = by << 6, col0 = bx << 6;
    const int w = t >> 6, lane = t & 63, quad = lane >> 4, lm = lane & 15;
    const int r0 = t >> 3, c0 = (t & 7) << 3;
    const int wr0 = r0 * 64 + (c0 ^ ((r0 & 7) << 3));
    const int dtW = flags[2];
    const int dtOut = flags[1];

    const unsigned short* xp  = X  + (size_t)(row0 + r0) * 768 + c0;
    const unsigned short* xp2 = xp + 32 * 768;
    const unsigned short* wp  = WT + (size_t)(col0 + r0) * 768 + c0;
    const unsigned short* wp2 = wp + 32 * 768;

    uint4 a0 = *(const uint4*)xp,  a1 = *(const uint4*)xp2;
    uint4 g0 = *(const uint4*)wp,  g1 = *(const uint4*)wp2;

    f32x4 acc[4];
    #pragma unroll
    for (int i = 0; i < 4; i++) acc[i] = (f32x4){0.f, 0.f, 0.f, 0.f};

    const int am = (w << 4) + lm;
    const int abase = am * 64, akey = (am & 7) << 3;

    for (int k0 = 0;;) {
        __syncthreads();
        *(uint4*)&At[wr0] = a0;        *(uint4*)&At[wr0 + 2048] = a1;
        *(uint4*)&Bt[wr0] = g0;        *(uint4*)&Bt[wr0 + 2048] = g1;
        __syncthreads();
        k0 += 64;
        if (k0 < 768) {
            a0 = *(const uint4*)(xp + k0);  a1 = *(const uint4*)(xp2 + k0);
            g0 = *(const uint4*)(wp + k0);  g1 = *(const uint4*)(wp2 + k0);
        }
        #pragma unroll
        for (int ks = 0; ks < 2; ks++) {
            int ko = (quad << 3) + (ks << 5);
            bf16x8 afr = *(const bf16x8*)&At[abase + (ko ^ akey)];
            #pragma unroll
            for (int t4 = 0; t4 < 4; t4++) {
                int bn = (t4 << 4) + lm;
                bf16x8 bfr = *(const bf16x8*)&Bt[bn * 64 + (ko ^ ((bn & 7) << 3))];
                acc[t4] = __builtin_amdgcn_mfma_f32_16x16x32_bf16(afr, bfr, acc[t4], 0, 0, 0);
            }
        }
        if (k0 >= 768) break;
    }

    if (mode == 1 && dtOut) {
        #pragma unroll
        for (int t4 = 0; t4 < 4; t4++) {
            int col = col0 + (t4 << 4) + lm;
            float bsv = loadF(bias, col, dtW);
            #pragma unroll
            for (int rg = 0; rg < 4; rg++) {
                int row = row0 + (w << 4) + (quad << 2) + rg;
                ((float*)dst)[(size_t)row * 768 + col] = acc[t4][rg] + bsv;
            }
        }
        return;
    }

    __syncthreads();
    #pragma unroll
    for (int t4 = 0; t4 < 4; t4++) {
        int colL = (t4 << 4) + lm;
        float bsv = loadF(bias, col0 + colL, dtW);
        #pragma unroll
        for (int rg = 0; rg < 4; rg++) {
            int rowL = (w << 4) + (quad << 2) + rg;
            unsigned short hv = f2b(acc[t4][rg] + bsv);
            if (mode == 2) smem[colL * 72 + rowL] = hv;
            else           smem[rowL * 72 + colL] = hv;
        }
    }
    __syncthreads();
    const int g = t >> 2, cc = (t & 3) << 4;
    uint4 o0 = *(const uint4*)&smem[g * 72 + cc];
    uint4 o1 = *(const uint4*)&smem[g * 72 + cc + 8];
    unsigned short* o;
    if (mode == 0) {
        int b = row0 >> 9, n0b = row0 & 511, h = col0 >> 6;
        o = (unsigned short*)dst + ((size_t)(b * 12 + h) * 512 + n0b + g) * 64 + cc;
    } else if (mode == 2) {
        int b = row0 >> 9, n0b = row0 & 511, h = col0 >> 6;
        o = (unsigned short*)dst + ((size_t)(b * 12 + h) * 64 + g) * 512 + n0b + cc;
    } else {
        o = (unsigned short*)dst + (size_t)(row0 + g) * 768 + col0 + cc;
    }
    *(uint4*)o = o0;
    *(uint4*)(o + 8) = o1;
}

// ---------------------------------------------------------------------------
// MFMA attention. Block = 16 Q rows of one (b,h). 4 waves.
// 1-D grid, id = bh + 96*qb (XCD-resident K/V).
// Round 9: K loads batched (kv[16]) before QK^T; V loads (vv[16]) issued
// before phase 2 so their latency hides under softmax VALU work.
// ---------------------------------------------------------------------------
__global__ __launch_bounds__(256) void attn_kernel(
        const unsigned short* __restrict__ qh, const unsigned short* __restrict__ kh,
        const unsigned short* __restrict__ vT, const unsigned int* __restrict__ pm,
        const float* __restrict__ alphas, unsigned short* __restrict__ atted)
{
    __shared__ unsigned short P[16 * 512];
    __shared__ float Zp[4][16][3];
    __shared__ unsigned short Ost[16 * 72];
    const int t = threadIdx.x;
    const int w = t >> 6, lane = t & 63, quad = lane >> 4, lm = lane & 15;
    const int id = blockIdx.x;
    const int bh = id % 96, qb = id / 96;
    const int b = bh / 12, h = bh % 12;
    const int n0 = qb << 4;

    const unsigned short* qrow = qh + ((size_t)(bh * 512 + n0 + lm)) * 64 + (quad << 3);
    bf16x8 qa0 = *(const bf16x8*)qrow;
    bf16x8 qa1 = *(const bf16x8*)(qrow + 32);

    // ---- phase 1: batch all K loads, then MFMA ----
    const unsigned short* kb0 = kh + ((size_t)(bh * 512 + (w << 7) + lm)) * 64 + (quad << 3);
    uint4 kv[16];
    #pragma unroll
    for (int nt = 0; nt < 8; nt++) {
        const unsigned short* kr = kb0 + nt * (16 * 64);
        kv[2 * nt]     = *(const uint4*)kr;
        kv[2 * nt + 1] = *(const uint4*)(kr + 32);
    }
    f32x4 acc[8];
    #pragma unroll
    for (int i = 0; i < 8; i++) acc[i] = (f32x4){0.f, 0.f, 0.f, 0.f};
    #pragma unroll
    for (int nt = 0; nt < 8; nt++) {
        acc[nt] = __builtin_amdgcn_mfma_f32_16x16x32_bf16(qa0, u2b(kv[2 * nt]), acc[nt], 0, 0, 0);
        acc[nt] = __builtin_amdgcn_mfma_f32_16x16x32_bf16(qa1, u2b(kv[2 * nt + 1]), acc[nt], 0, 0, 0);
    }

    // ---- issue V loads now; latency hides under phase 2 ----
    const unsigned short* vb = vT + ((size_t)(bh * 64 + (w << 4) + lm)) * 512 + (quad << 3);
    uint4 vv[16];
    #pragma unroll
    for (int ks = 0; ks < 16; ks++) vv[ks] = *(const uint4*)(vb + (ks << 5));

    // ---- phase 2: exp, masked Z, combined P ----
    float al[3];
    #pragma unroll
    for (int l = 0; l < 3; l++) al[l] = alphas[b * 3 + l];

    #pragma unroll
    for (int nt = 0; nt < 8; nt++)
        #pragma unroll
        for (int rg = 0; rg < 4; rg++)
            acc[nt][rg] = __expf(acc[nt][rg] * 0.125f);

    unsigned int mkw[4][3];
    #pragma unroll
    for (int rg = 0; rg < 4; rg++)
        #pragma unroll
        for (int l = 0; l < 3; l++)
            mkw[rg][l] = pm[((size_t)((l << 3) + b) * 512 + n0 + (quad << 2) + rg) * 16 + lm]
                         >> (w << 3);

    #pragma unroll
    for (int rg = 0; rg < 4; rg++) {
        float z0 = 0.f, z1 = 0.f, z2 = 0.f;
        #pragma unroll
        for (int nt = 0; nt < 8; nt++) {
            float e = acc[nt][rg];
            if (!((mkw[rg][0] >> nt) & 1)) z0 += e;
            if (!((mkw[rg][1] >> nt) & 1)) z1 += e;
            if (!((mkw[rg][2] >> nt) & 1)) z2 += e;
        }
        #pragma unroll
        for (int off = 1; off < 16; off <<= 1) {
            z0 += __shfl_xor(z0, off);
            z1 += __shfl_xor(z1, off);
            z2 += __shfl_xor(z2, off);
        }
        if (lm == 0) {
            int row = (quad << 2) + rg;
            Zp[w][row][0] = z0; Zp[w][row][1] = z1; Zp[w][row][2] = z2;
        }
    }
    __syncthreads();

    #pragma unroll
    for (int rg = 0; rg < 4; rg++) {
        int row = (quad << 2) + rg;
        float coef[3]; float addu = 0.f;
        #pragma unroll
        for (int l = 0; l < 3; l++) {
            float Z = Zp[0][row][l] + Zp[1][row][l] + Zp[2][row][l] + Zp[3][row][l];
            if (Z > 0.f) coef[l] = al[l] / Z;
            else { coef[l] = 0.f; addu += al[l] * (1.0f / 512.0f); }
        }
        #pragma unroll
        for (int nt = 0; nt < 8; nt++) {
            int g = (w << 3) + nt;
            float p = addu;
            float e = acc[nt][rg];
            if (!((mkw[rg][0] >> nt) & 1)) p += coef[0] * e;
            if (!((mkw[rg][1] >> nt) & 1)) p += coef[1] * e;
            if (!((mkw[rg][2] >> nt) & 1)) p += coef[2] * e;
            int c = (g << 4) + lm;
            int chunk = c >> 3, j = c & 7;
            P[row * 512 + (((chunk ^ (row & 7))) << 3) + j] = f2b(p);
        }
    }
    __syncthreads();

    // ---- phase 3: O = P @ V (V already in registers) ----
    f32x4 accO = (f32x4){0.f, 0.f, 0.f, 0.f};
    #pragma unroll
    for (int ks = 0; ks < 16; ks++) {
        bf16x8 pa = *(const bf16x8*)&P[lm * 512 + ((((ks << 2) + quad) ^ (lm & 7)) << 3)];
        accO = __builtin_amdgcn_mfma_f32_16x16x32_bf16(pa, u2b(vv[ks]), accO, 0, 0, 0);
    }
    #pragma unroll
    for (int rg = 0; rg < 4; rg++)
        Ost[((quad << 2) + rg) * 72 + (w << 4) + lm] = f2b(accO[rg]);
    __syncthreads();
    const int r2 = t >> 4, c4 = t & 15;
    uint2 val = *(const uint2*)&Ost[r2 * 72 + (c4 << 2)];
    *(uint2*)&atted[((size_t)(b * 512 + n0 + r2)) * 768 + (h << 6) + (c4 << 2)] = val;
}

// ---------------------------------------------------------------------------
extern "C" void kernel_launch(void* const* d_in, const int* in_sizes, int n_in,
                              void* d_out, int out_size, void* d_ws, size_t ws_size,
                              hipStream_t stream)
{
    const void* v  = d_in[0];
    const void* k  = d_in[1];
    const void* q  = d_in[2];
    const void* mk = d_in[3];
    const void* Wv = d_in[6];
    const void* bv = d_in[7];
    const void* Wk = d_in[8];
    const void* bk = d_in[9];
    const void* Wq = d_in[10];
    const void* bq = d_in[11];
    const void* Wm = d_in[12];
    const void* bm = d_in[13];
    const void* pool_w = d_in[14];
    const void* pool_b = d_in[15];
    const void* w1 = d_in[16];
    const void* w2 = d_in[17];
    const void* b2 = d_in[18];

    char* ws = (char*)d_ws;
    int*   flags  = (int*)ws;                                   // 64 B
    float* alphas = (float*)(ws + 256);
    float* scores = (float*)(ws + 512);                         // 16 KB
    float* scs    = (float*)(ws + 16896);                       // 16 KB
    float* ppart  = (float*)(ws + 33280);                       // 196 KB
    float* plog   = (float*)(ws + 229888);                      // 1.2 KB
    unsigned int* pm = (unsigned int*)(ws + 262144);            // 786 KB
    unsigned short* qh  = (unsigned short*)(ws + 1048576);      // 6.29 MB each
    unsigned short* kh  = (unsigned short*)(ws + 1048576 + 1 * 6291456L);
    unsigned short* vT  = (unsigned short*)(ws + 1048576 + 2 * 6291456L);
    unsigned short* vb  = (unsigned short*)(ws + 1048576 + 3 * 6291456L);
    unsigned short* kb  = (unsigned short*)(ws + 1048576 + 4 * 6291456L);
    unsigned short* qb  = (unsigned short*)(ws + 1048576 + 5 * 6291456L);
    unsigned short* atted = vb;  // alias: vb dead by attention time
    char* wt0 = ws + 1048576 + 6 * 6291456L;                    // 1.18 MB each
    unsigned short* WTv = (unsigned short*)(wt0);
    unsigned short* WTk = (unsigned short*)(wt0 + 1 * 1179648L);
    unsigned short* WTq = (unsigned short*)(wt0 + 2 * 1179648L);
    unsigned short* WTm = (unsigned short*)(wt0 + 3 * 1179648L);

    sniff_kernel<<<dim3(1), dim3(256), 0, stream>>>(
        (const unsigned int*)mk, (const unsigned int*)v, (const unsigned int*)Wv, flags);
    conv_act_kernel<<<dim3(1536, 3), dim3(256), 0, stream>>>(v, k, q, flags, vb, kb, qb);
    conv_wt_kernel<<<dim3(144, 4), dim3(256), 0, stream>>>(
        Wv, Wk, Wq, Wm, flags, WTv, WTk, WTq, WTm);
    pack_kernel<<<dim3(384), dim3(256), 0, stream>>>(mk, flags, pm);
    route_score_kernel<<<dim3(64), dim3(256), 0, stream>>>(v, pool_w, pool_b, flags, scores);
    route_softmax_kernel<<<dim3(8), dim3(512), 0, stream>>>(scores, scs);
    route_pool_kernel<<<dim3(8, 8), dim3(256), 0, stream>>>(v, flags, scs, ppart);
    route_hid_kernel<<<dim3(12, 8), dim3(256), 0, stream>>>(w1, w2, flags, ppart, plog);
    route_alpha_kernel<<<dim3(8), dim3(64), 0, stream>>>(b2, flags, plog, alphas);
    gemm3_kernel<<<dim3(768, 3), dim3(256), 0, stream>>>(
        vb, kb, qb, WTv, WTk, WTq, bv, bk, bq, flags,
        (void*)vT, (void*)kh, (void*)qh, 2, 0, 0);
    attn_kernel<<<dim3(3072), dim3(256), 0, stream>>>(qh, kh, vT, pm, alphas, atted);
    gemm3_kernel<<<dim3(768, 1), dim3(256), 0, stream>>>(
        atted, atted, atted, WTm, WTm, WTm, bm, bm, bm, flags,
        d_out, d_out, d_out, 1, 1, 1);
}

// Round 10
// 299.010 us; speedup vs baseline: 1.0445x; 1.0445x over previous
//
#include <hip/hip_runtime.h>
#include <hip/hip_bf16.h>
#include <stdint.h>

// ---------------------------------------------------------------------------
// SARoutingBlock. Round 10: best-known combo. attn = r7 mask logic (no
// pre-shift; VGPR headroom) + r9 K-batching (one exposed latency), V loads
// back in the phase-3 loop (no 64-VGPR pin). Routing pool/score read bf16 vb
// (half the traffic). GEMMs/pack/conv unchanged from round 8.
// ---------------------------------------------------------------------------

typedef __bf16 bf16x8 __attribute__((ext_vector_type(8)));
typedef float f32x4 __attribute__((ext_vector_type(4)));

#define NEGV -1e9f

__device__ __forceinline__ float b2f(unsigned short h) {
    union { unsigned int u; float f; } x; x.u = ((unsigned int)h) << 16; return x.f;
}
__device__ __forceinline__ unsigned short f2b(float f) {
    union { float f; unsigned int u; } x; x.f = f;
    unsigned int u = x.u + 0x7FFFu + ((x.u >> 16) & 1u);
    return (unsigned short)(u >> 16);
}
__device__ __forceinline__ unsigned int packbf(unsigned int u0, unsigned int u1) {
    unsigned int r0 = (u0 + 0x7FFFu + ((u0 >> 16) & 1u)) >> 16;
    unsigned int r1 = (u1 + 0x7FFFu + ((u1 >> 16) & 1u)) & 0xFFFF0000u;
    return r0 | r1;
}
__device__ __forceinline__ uint4 load8bf(const void* base, size_t elemOff, int isF32) {
    if (!isF32) return *(const uint4*)((const unsigned short*)base + elemOff);
    const uint4* f = (const uint4*)((const float*)base + elemOff);
    uint4 a = f[0], b = f[1];
    uint4 r;
    r.x = packbf(a.x, a.y);
    r.y = packbf(a.z, a.w);
    r.z = packbf(b.x, b.y);
    r.w = packbf(b.z, b.w);
    return r;
}
__device__ __forceinline__ float loadF(const void* p, int idx, int isF32) {
    return isF32 ? ((const float*)p)[idx] : b2f(((const unsigned short*)p)[idx]);
}
__device__ __forceinline__ bf16x8 u2b(uint4 u) {
    union { uint4 a; bf16x8 b; } x; x.a = u; return x.b;
}

// ---------------------------------------------------------------------------
// Sniffer: flags[0]=mask mode (0=i32,1=u8,2=f32,3=bf16); flags[1]=v/k/q dtype
// (0=bf16,1=f32); flags[2]=weights dtype.
// ---------------------------------------------------------------------------
__global__ void sniff_kernel(const unsigned int* __restrict__ mp,
                             const unsigned int* __restrict__ vp,
                             const unsigned int* __restrict__ wp,
                             int* __restrict__ flags)
{
    __shared__ int oki, oku, okf, badv, badw;
    if (threadIdx.x == 0) { oki = 1; oku = 1; okf = 1; badv = 0; badw = 0; }
    __syncthreads();
    int li = 1, lu = 1, lf = 1, bv = 0, bw = 0;
    for (int i = threadIdx.x; i < 16384; i += 256) {
        unsigned int w = mp[i];
        if (w > 1u) li = 0;
        if (w & 0xFEFEFEFEu) lu = 0;
        if (w != 0u && w != 0x3F800000u) lf = 0;
    }
    for (int i = threadIdx.x; i < 8192; i += 256) {
        unsigned int w = vp[i];
        float f0 = b2f((unsigned short)(w & 0xFFFF));
        float f1 = b2f((unsigned short)(w >> 16));
        if (!(fabsf(f0) < 1e4f) || !(fabsf(f1) < 1e4f)) bv = 1;
        w = wp[i];
        f0 = b2f((unsigned short)(w & 0xFFFF));
        f1 = b2f((unsigned short)(w >> 16));
        if (!(fabsf(f0) < 1e4f) || !(fabsf(f1) < 1e4f)) bw = 1;
    }
    if (!li) atomicAnd(&oki, 0);
    if (!lu) atomicAnd(&oku, 0);
    if (!lf) atomicAnd(&okf, 0);
    if (bv) atomicOr(&badv, 1);
    if (bw) atomicOr(&badw, 1);
    __syncthreads();
    if (threadIdx.x == 0) {
        flags[0] = oki ? 0 : (oku ? 1 : (okf ? 2 : 3));
        flags[1] = badv;
        flags[2] = badw;
    }
}

// ---------------------------------------------------------------------------
// conv_act: v,k,q -> contiguous bf16 copies. Grid (1536, 3) x 256 thr, 8/thr.
// ---------------------------------------------------------------------------
__global__ __launch_bounds__(256) void conv_act_kernel(
        const void* __restrict__ v, const void* __restrict__ k,
        const void* __restrict__ q, const int* __restrict__ flags,
        unsigned short* __restrict__ vb, unsigned short* __restrict__ kb,
        unsigned short* __restrict__ qb)
{
    const int dtV = flags[1];
    const int which = blockIdx.y;
    const void* src = (which == 0) ? v : (which == 1) ? k : q;
    unsigned short* dst = (which == 0) ? vb : (which == 1) ? kb : qb;
    size_t off = ((size_t)blockIdx.x * 256 + threadIdx.x) * 8;
    uint4 r = load8bf(src, off, dtV);
    *(uint4*)(dst + off) = r;
}

// ---------------------------------------------------------------------------
// conv_wt: W[768][768] -> WT bf16 [n][k] (transposed). Grid (144, 4), 256 thr.
// ---------------------------------------------------------------------------
__global__ __launch_bounds__(256) void conv_wt_kernel(
        const void* __restrict__ W0, const void* __restrict__ W1,
        const void* __restrict__ W2, const void* __restrict__ W3,
        const int* __restrict__ flags,
        unsigned short* __restrict__ T0, unsigned short* __restrict__ T1,
        unsigned short* __restrict__ T2, unsigned short* __restrict__ T3)
{
    __shared__ unsigned short tile[64][65];
    const int t = threadIdx.x;
    const int dtW = flags[2];
    const int which = blockIdx.y;
    const void* W = (which == 0) ? W0 : (which == 1) ? W1 : (which == 2) ? W2 : W3;
    unsigned short* T = (which == 0) ? T0 : (which == 1) ? T1 : (which == 2) ? T2 : T3;
    const int tk = (blockIdx.x / 12) << 6;
    const int tn = (blockIdx.x % 12) << 6;
    #pragma unroll
    for (int i = 0; i < 16; i++) {
        int idx = (i << 8) + t;
        int r = idx >> 6, c = idx & 63;
        tile[r][c] = f2b(loadF(W, (tk + r) * 768 + tn + c, dtW));
    }
    __syncthreads();
    #pragma unroll
    for (int i = 0; i < 16; i++) {
        int idx = (i << 8) + t;
        int rn = idx >> 6, ck = idx & 63;
        T[(size_t)(tn + rn) * 768 + tk + ck] = tile[ck][rn];
    }
}

// ---------------------------------------------------------------------------
// Mask bit-pack: pm[grow*16 + lm], grow = (l*8+b)*512 + n,
// bit g = mask[l,b,n, g*16+lm]. One block packs 32 rows.
// ---------------------------------------------------------------------------
__global__ __launch_bounds__(256) void pack_kernel(
        const void* __restrict__ masks, const int* __restrict__ flags,
        unsigned int* __restrict__ pm)
{
    __shared__ unsigned char flg[32 * 512];
    const int t = threadIdx.x;
    const int mode = flags[0];
    const size_t e0 = (size_t)blockIdx.x * (32 * 512);
    if (mode == 0 || mode == 2) {
        const uint4* p = (const uint4*)((const unsigned int*)masks + e0);
        for (int i = t; i < 4096; i += 256) {
            uint4 u = p[i];
            int base = i << 2;
            flg[base + 0] = u.x ? 1 : 0;
            flg[base + 1] = u.y ? 1 : 0;
            flg[base + 2] = u.z ? 1 : 0;
            flg[base + 3] = u.w ? 1 : 0;
        }
    } else if (mode == 1) {
        const uint4* p = (const uint4*)((const unsigned char*)masks + e0);
        for (int i = t; i < 1024; i += 256) {
            uint4 u = p[i];
            unsigned int uu[4] = {u.x, u.y, u.z, u.w};
            int base = i << 4;
            #pragma unroll
            for (int k2 = 0; k2 < 4; k2++)
                #pragma unroll
                for (int bb = 0; bb < 4; bb++)
                    flg[base + k2 * 4 + bb] = ((uu[k2] >> (bb * 8)) & 0xFFu) ? 1 : 0;
        }
    } else {
        const uint4* p = (const uint4*)((const unsigned short*)masks + e0);
        for (int i = t; i < 2048; i += 256) {
            uint4 u = p[i];
            unsigned int uu[4] = {u.x, u.y, u.z, u.w};
            int base = i << 3;
            #pragma unroll
            for (int k2 = 0; k2 < 4; k2++) {
                flg[base + k2 * 2 + 0] = (uu[k2] & 0xFFFFu) ? 1 : 0;
                flg[base + k2 * 2 + 1] = (uu[k2] >> 16) ? 1 : 0;
            }
        }
    }
    __syncthreads();
    for (int widx = t; widx < 512; widx += 256) {
        int rl = widx >> 4, lm = widx & 15;
        unsigned int bits = 0;
        #pragma unroll
        for (int g = 0; g < 32; g++)
            bits |= ((unsigned int)(flg[rl * 512 + (g << 4) + lm] & 1)) << g;
        pm[(size_t)blockIdx.x * 512 + widx] = bits;
    }
}

// ---------------------------------------------------------------------------
// Routing stage 1: pooling scores per row from bf16 vb. 64 rows/block.
// ---------------------------------------------------------------------------
__global__ __launch_bounds__(256) void route_score_kernel(
        const unsigned short* __restrict__ vb, const void* __restrict__ pool_w,
        const void* __restrict__ pool_b, const int* __restrict__ flags,
        float* __restrict__ scores)
{
    __shared__ float pw[768];
    const int t = threadIdx.x;
    const int b = blockIdx.x >> 3, ch = blockIdx.x & 7;
    const int dtW = flags[2];
    for (int d = t; d < 768; d += 256) pw[d] = loadF(pool_w, d, dtW);
    __syncthreads();
    const int r = t >> 2, c4 = t & 3;
    const int n = (ch << 6) + r;
    const unsigned int* vr = (const unsigned int*)vb + ((size_t)(b * 512 + n)) * 384;
    float dot = 0.f, asum = 0.f;
    for (int j = 0; j < 96; j++) {
        int p = c4 + (j << 2);
        unsigned int u = vr[p];
        float f0 = b2f((unsigned short)(u & 0xFFFF));
        float f1 = b2f((unsigned short)(u >> 16));
        asum += fabsf(f0) + fabsf(f1);
        dot += f0 * pw[2 * p] + f1 * pw[2 * p + 1];
    }
    dot += __shfl_xor(dot, 1); dot += __shfl_xor(dot, 2);
    asum += __shfl_xor(asum, 1); asum += __shfl_xor(asum, 2);
    if (c4 == 0)
        scores[b * 512 + n] = (asum == 0.f) ? NEGV : dot + loadF(pool_b, 0, dtW);
}

// ---------------------------------------------------------------------------
// Routing stage 2: softmax over N per batch -> scs. 8 blocks x 512.
// ---------------------------------------------------------------------------
__global__ __launch_bounds__(512) void route_softmax_kernel(
        const float* __restrict__ scores, float* __restrict__ scs)
{
    __shared__ float red[8];
    const int t = threadIdx.x, b = blockIdx.x;
    float scv = scores[b * 512 + t];
    float mx = scv;
    #pragma unroll
    for (int off = 1; off < 64; off <<= 1) mx = fmaxf(mx, __shfl_xor(mx, off));
    if ((t & 63) == 0) red[t >> 6] = mx;
    __syncthreads();
    float M = red[0];
    #pragma unroll
    for (int i = 1; i < 8; i++) M = fmaxf(M, red[i]);
    float e = __expf(scv - M);
    __syncthreads();
    float sm = e;
    #pragma unroll
    for (int off = 1; off < 64; off <<= 1) sm += __shfl_xor(sm, off);
    if ((t & 63) == 0) red[t >> 6] = sm;
    __syncthreads();
    float SS = 0.f;
    #pragma unroll
    for (int i = 0; i < 8; i++) SS += red[i];
    scs[b * 512 + t] = e / SS;
}

// ---------------------------------------------------------------------------
// Routing stage 3: partial pooled sums from bf16 vb. Grid (8, 8), 256 thr.
// ---------------------------------------------------------------------------
__global__ __launch_bounds__(256) void route_pool_kernel(
        const unsigned short* __restrict__ vbuf, const int* __restrict__ flags,
        const float* __restrict__ scs, float* __restrict__ ppart)
{
    __shared__ float ps[64];
    const int t = threadIdx.x;
    const int ch = blockIdx.x, b = blockIdx.y;
    if (t < 64) ps[t] = scs[b * 512 + (ch << 6) + t];
    __syncthreads();
    const int d0 = t * 3;
    float a0 = 0.f, a1 = 0.f, a2 = 0.f;
    const unsigned short* vp = vbuf + ((size_t)(b * 512 + (ch << 6))) * 768 + d0;
    #pragma unroll 4
    for (int r = 0; r < 64; r++) {
        float p = ps[r];
        a0 += b2f(vp[0]) * p; a1 += b2f(vp[1]) * p; a2 += b2f(vp[2]) * p;
        vp += 768;
    }
    float* o = ppart + ((size_t)(b * 8 + ch)) * 768 + d0;
    o[0] = a0; o[1] = a1; o[2] = a2;
}

// ---------------------------------------------------------------------------
// Routing stage 4: hidden units + partial logits. Grid (12 jc, 8 b), 256 thr.
// ---------------------------------------------------------------------------
__global__ __launch_bounds__(256) void route_hid_kernel(
        const void* __restrict__ w1, const void* __restrict__ w2,
        const int* __restrict__ flags, const float* __restrict__ ppart,
        float* __restrict__ plog)
{
    __shared__ float pool[768];
    __shared__ float red[4][32];
    const int t = threadIdx.x;
    const int jc = blockIdx.x, b = blockIdx.y;
    const int dtW = flags[2];
    for (int d = t; d < 768; d += 256) {
        float a = 0.f;
        #pragma unroll
        for (int c = 0; c < 8; c++) a += ppart[((size_t)(b * 8 + c)) * 768 + d];
        pool[d] = a;
    }
    __syncthreads();
    const int jo = (t & 3) << 3;
    const int dr = t >> 2;
    float acc[8];
    #pragma unroll
    for (int j = 0; j < 8; j++) acc[j] = 0.f;
    for (int it = 0; it < 12; it++) {
        int d = (it << 6) + dr;
        float pv = pool[d];
        size_t off = (size_t)d * 384 + (jc << 5) + jo;
        if (!dtW) {
            uint4 u = *(const uint4*)((const unsigned short*)w1 + off);
            unsigned int uu[4] = {u.x, u.y, u.z, u.w};
            #pragma unroll
            for (int j2 = 0; j2 < 4; j2++) {
                acc[2 * j2]     += pv * b2f((unsigned short)(uu[j2] & 0xFFFF));
                acc[2 * j2 + 1] += pv * b2f((unsigned short)(uu[j2] >> 16));
            }
        } else {
            const float4* f = (const float4*)((const float*)w1 + off);
            float4 u0 = f[0], u1 = f[1];
            acc[0] += pv * u0.x; acc[1] += pv * u0.y;
            acc[2] += pv * u0.z; acc[3] += pv * u0.w;
            acc[4] += pv * u1.x; acc[5] += pv * u1.y;
            acc[6] += pv * u1.z; acc[7] += pv * u1.w;
        }
    }
    #pragma unroll
    for (int off = 4; off < 64; off <<= 1)
        #pragma unroll
        for (int j = 0; j < 8; j++) acc[j] += __shfl_xor(acc[j], off);
    const int w = t >> 6, lane = t & 63;
    if (lane < 4) {
        #pragma unroll
        for (int j = 0; j < 8; j++) red[w][lane * 8 + j] = acc[j];
    }
    __syncthreads();
    if (t < 32) {
        float h = red[0][t] + red[1][t] + red[2][t] + red[3][t];
        h = fmaxf(h, 0.f);
        int jg = (jc << 5) + t;
        float l0 = h * loadF(w2, jg * 3 + 0, dtW);
        float l1 = h * loadF(w2, jg * 3 + 1, dtW);
        float l2 = h * loadF(w2, jg * 3 + 2, dtW);
        #pragma unroll
        for (int off = 1; off < 32; off <<= 1) {
            l0 += __shfl_xor(l0, off);
            l1 += __shfl_xor(l1, off);
            l2 += __shfl_xor(l2, off);
        }
        if (t == 0) {
            float* o = plog + ((size_t)(b * 12 + jc)) * 3;
            o[0] = l0; o[1] = l1; o[2] = l2;
        }
    }
}

// ---------------------------------------------------------------------------
// Routing stage 5: reduce partial logits, softmax -> alphas. 8 tiny blocks.
// ---------------------------------------------------------------------------
__global__ __launch_bounds__(64) void route_alpha_kernel(
        const void* __restrict__ b2, const int* __restrict__ flags,
        const float* __restrict__ plog, float* __restrict__ alphas)
{
    const int t = threadIdx.x, b = blockIdx.x;
    if (t == 0) {
        const int dtW = flags[2];
        float lg[3];
        #pragma unroll
        for (int l = 0; l < 3; l++) {
            float a = loadF(b2, l, dtW);
            for (int jc = 0; jc < 12; jc++) a += plog[((size_t)(b * 12 + jc)) * 3 + l];
            lg[l] = a;
        }
        float mm = fmaxf(lg[0], fmaxf(lg[1], lg[2]));
        float e0 = __expf(lg[0] - mm), e1 = __expf(lg[1] - mm), e2 = __expf(lg[2] - mm);
        float ss = e0 + e1 + e2;
        alphas[b * 3 + 0] = e0 / ss;
        alphas[b * 3 + 1] = e1 / ss;
        alphas[b * 3 + 2] = e2 / ss;
    }
}

// ---------------------------------------------------------------------------
// Pipelined MFMA bf16 GEMM, up to 3 sub-gemms selected by blockIdx.y.
// BK=64 (12 steps), register prefetch across the barrier. LDS 16 KB.
// ---------------------------------------------------------------------------
__global__ __launch_bounds__(256) void gemm3_kernel(
        const unsigned short* __restrict__ X0, const unsigned short* __restrict__ X1,
        const unsigned short* __restrict__ X2,
        const unsigned short* __restrict__ W0, const unsigned short* __restrict__ W1,
        const unsigned short* __restrict__ W2,
        const void* __restrict__ bias0, const void* __restrict__ bias1,
        const void* __restrict__ bias2,
        const int* __restrict__ flags,
        void* __restrict__ dst0, void* __restrict__ dst1, void* __restrict__ dst2,
        int m0, int m1, int m2)
{
    __shared__ unsigned short smem[8192];   // At[4096] + Bt[4096], 16 KB
    unsigned short* At = smem;
    unsigned short* Bt = smem + 4096;
    const int t = threadIdx.x;
    const int which = blockIdx.y;
    const unsigned short* X  = (which == 0) ? X0 : (which == 1) ? X1 : X2;
    const unsigned short* WT = (which == 0) ? W0 : (which == 1) ? W1 : W2;
    const void* bias = (which == 0) ? bias0 : (which == 1) ? bias1 : bias2;
    void* dst = (which == 0) ? dst0 : (which == 1) ? dst1 : dst2;
    const int mode = (which == 0) ? m0 : (which == 1) ? m1 : m2;

    const int id = blockIdx.x;
    const int bx = id >> 6, by = id & 63;
    const int row0 = by << 6, col0 = bx << 6;
    const int w = t >> 6, lane = t & 63, quad = lane >> 4, lm = lane & 15;
    const int r0 = t >> 3, c0 = (t & 7) << 3;
    const int wr0 = r0 * 64 + (c0 ^ ((r0 & 7) << 3));
    const int dtW = flags[2];
    const int dtOut = flags[1];

    const unsigned short* xp  = X  + (size_t)(row0 + r0) * 768 + c0;
    const unsigned short* xp2 = xp + 32 * 768;
    const unsigned short* wp  = WT + (size_t)(col0 + r0) * 768 + c0;
    const unsigned short* wp2 = wp + 32 * 768;

    uint4 a0 = *(const uint4*)xp,  a1 = *(const uint4*)xp2;
    uint4 g0 = *(const uint4*)wp,  g1 = *(const uint4*)wp2;

    f32x4 acc[4];
    #pragma unroll
    for (int i = 0; i < 4; i++) acc[i] = (f32x4){0.f, 0.f, 0.f, 0.f};

    const int am = (w << 4) + lm;
    const int abase = am * 64, akey = (am & 7) << 3;

    for (int k0 = 0;;) {
        __syncthreads();
        *(uint4*)&At[wr0] = a0;        *(uint4*)&At[wr0 + 2048] = a1;
        *(uint4*)&Bt[wr0] = g0;        *(uint4*)&Bt[wr0 + 2048] = g1;
        __syncthreads();
        k0 += 64;
        if (k0 < 768) {
            a0 = *(const uint4*)(xp + k0);  a1 = *(const uint4*)(xp2 + k0);
            g0 = *(const uint4*)(wp + k0);  g1 = *(const uint4*)(wp2 + k0);
        }
        #pragma unroll
        for (int ks = 0; ks < 2; ks++) {
            int ko = (quad << 3) + (ks << 5);
            bf16x8 afr = *(const bf16x8*)&At[abase + (ko ^ akey)];
            #pragma unroll
            for (int t4 = 0; t4 < 4; t4++) {
                int bn = (t4 << 4) + lm;
                bf16x8 bfr = *(const bf16x8*)&Bt[bn * 64 + (ko ^ ((bn & 7) << 3))];
                acc[t4] = __builtin_amdgcn_mfma_f32_16x16x32_bf16(afr, bfr, acc[t4], 0, 0, 0);
            }
        }
        if (k0 >= 768) break;
    }

    if (mode == 1 && dtOut) {
        #pragma unroll
        for (int t4 = 0; t4 < 4; t4++) {
            int col = col0 + (t4 << 4) + lm;
            float bsv = loadF(bias, col, dtW);
            #pragma unroll
            for (int rg = 0; rg < 4; rg++) {
                int row = row0 + (w << 4) + (quad << 2) + rg;
                ((float*)dst)[(size_t)row * 768 + col] = acc[t4][rg] + bsv;
            }
        }
        return;
    }

    __syncthreads();
    #pragma unroll
    for (int t4 = 0; t4 < 4; t4++) {
        int colL = (t4 << 4) + lm;
        float bsv = loadF(bias, col0 + colL, dtW);
        #pragma unroll
        for (int rg = 0; rg < 4; rg++) {
            int rowL = (w << 4) + (quad << 2) + rg;
            unsigned short hv = f2b(acc[t4][rg] + bsv);
            if (mode == 2) smem[colL * 72 + rowL] = hv;
            else           smem[rowL * 72 + colL] = hv;
        }
    }
    __syncthreads();
    const int g = t >> 2, cc = (t & 3) << 4;
    uint4 o0 = *(const uint4*)&smem[g * 72 + cc];
    uint4 o1 = *(const uint4*)&smem[g * 72 + cc + 8];
    unsigned short* o;
    if (mode == 0) {
        int b = row0 >> 9, n0b = row0 & 511, h = col0 >> 6;
        o = (unsigned short*)dst + ((size_t)(b * 12 + h) * 512 + n0b + g) * 64 + cc;
    } else if (mode == 2) {
        int b = row0 >> 9, n0b = row0 & 511, h = col0 >> 6;
        o = (unsigned short*)dst + ((size_t)(b * 12 + h) * 64 + g) * 512 + n0b + cc;
    } else {
        o = (unsigned short*)dst + (size_t)(row0 + g) * 768 + col0 + cc;
    }
    *(uint4*)o = o0;
    *(uint4*)(o + 8) = o1;
}

// ---------------------------------------------------------------------------
// MFMA attention. Block = 16 Q rows of one (b,h). 4 waves.
// 1-D grid, id = bh + 96*qb (XCD-resident K/V).
// K loads batched (kv[16], one exposed latency); V loads in phase-3 loop
// (no VGPR pin); mask words un-shifted (r7 form, keeps VGPR headroom).
// ---------------------------------------------------------------------------
__global__ __launch_bounds__(256) void attn_kernel(
        const unsigned short* __restrict__ qh, const unsigned short* __restrict__ kh,
        const unsigned short* __restrict__ vT, const unsigned int* __restrict__ pm,
        const float* __restrict__ alphas, unsigned short* __restrict__ atted)
{
    __shared__ unsigned short P[16 * 512];
    __shared__ float Zp[4][16][3];
    __shared__ unsigned short Ost[16 * 72];
    const int t = threadIdx.x;
    const int w = t >> 6, lane = t & 63, quad = lane >> 4, lm = lane & 15;
    const int id = blockIdx.x;
    const int bh = id % 96, qb = id / 96;
    const int b = bh / 12, h = bh % 12;
    const int n0 = qb << 4;

    const unsigned short* qrow = qh + ((size_t)(bh * 512 + n0 + lm)) * 64 + (quad << 3);
    bf16x8 qa0 = *(const bf16x8*)qrow;
    bf16x8 qa1 = *(const bf16x8*)(qrow + 32);

    // ---- phase 1: batch all K loads, then MFMA ----
    const unsigned short* kb0 = kh + ((size_t)(bh * 512 + (w << 7) + lm)) * 64 + (quad << 3);
    uint4 kv[16];
    #pragma unroll
    for (int nt = 0; nt < 8; nt++) {
        const unsigned short* kr = kb0 + nt * (16 * 64);
        kv[2 * nt]     = *(const uint4*)kr;
        kv[2 * nt + 1] = *(const uint4*)(kr + 32);
    }
    f32x4 acc[8];
    #pragma unroll
    for (int i = 0; i < 8; i++) acc[i] = (f32x4){0.f, 0.f, 0.f, 0.f};
    #pragma unroll
    for (int nt = 0; nt < 8; nt++) {
        acc[nt] = __builtin_amdgcn_mfma_f32_16x16x32_bf16(qa0, u2b(kv[2 * nt]), acc[nt], 0, 0, 0);
        acc[nt] = __builtin_amdgcn_mfma_f32_16x16x32_bf16(qa1, u2b(kv[2 * nt + 1]), acc[nt], 0, 0, 0);
    }

    // ---- phase 2: exp, masked Z, combined P ----
    float al[3];
    #pragma unroll
    for (int l = 0; l < 3; l++) al[l] = alphas[b * 3 + l];

    #pragma unroll
    for (int nt = 0; nt < 8; nt++)
        #pragma unroll
        for (int rg = 0; rg < 4; rg++)
            acc[nt][rg] = __expf(acc[nt][rg] * 0.125f);

    unsigned int mk[4][3];
    #pragma unroll
    for (int rg = 0; rg < 4; rg++)
        #pragma unroll
        for (int l = 0; l < 3; l++)
            mk[rg][l] = pm[((size_t)((l << 3) + b) * 512 + n0 + (quad << 2) + rg) * 16 + lm];

    #pragma unroll
    for (int rg = 0; rg < 4; rg++) {
        float z0 = 0.f, z1 = 0.f, z2 = 0.f;
        #pragma unroll
        for (int nt = 0; nt < 8; nt++) {
            int g = (w << 3) + nt;
            float e = acc[nt][rg];
            if (!((mk[rg][0] >> g) & 1)) z0 += e;
            if (!((mk[rg][1] >> g) & 1)) z1 += e;
            if (!((mk[rg][2] >> g) & 1)) z2 += e;
        }
        #pragma unroll
        for (int off = 1; off < 16; off <<= 1) {
            z0 += __shfl_xor(z0, off);
            z1 += __shfl_xor(z1, off);
            z2 += __shfl_xor(z2, off);
        }
        if (lm == 0) {
            int row = (quad << 2) + rg;
            Zp[w][row][0] = z0; Zp[w][row][1] = z1; Zp[w][row][2] = z2;
        }
    }
    __syncthreads();

    #pragma unroll
    for (int rg = 0; rg < 4; rg++) {
        int row = (quad << 2) + rg;
        float coef[3]; float addu = 0.f;
        #pragma unroll
        for (int l = 0; l < 3; l++) {
            float Z = Zp[0][row][l] + Zp[1][row][l] + Zp[2][row][l] + Zp[3][row][l];
            if (Z > 0.f) coef[l] = al[l] / Z;
            else { coef[l] = 0.f; addu += al[l] * (1.0f / 512.0f); }
        }
        #pragma unroll
        for (int nt = 0; nt < 8; nt++) {
            int g = (w << 3) + nt;
            float p = addu;
            float e = acc[nt][rg];
            if (!((mk[rg][0] >> g) & 1)) p += coef[0] * e;
            if (!((mk[rg][1] >> g) & 1)) p += coef[1] * e;
            if (!((mk[rg][2] >> g) & 1)) p += coef[2] * e;
            int c = (g << 4) + lm;
            int chunk = c >> 3, j = c & 7;
            P[row * 512 + (((chunk ^ (row & 7))) << 3) + j] = f2b(p);
        }
    }
    __syncthreads();

    // ---- phase 3: O = P @ V ----
    f32x4 accO = (f32x4){0.f, 0.f, 0.f, 0.f};
    const unsigned short* vb = vT + ((size_t)(bh * 64 + (w << 4) + lm)) * 512 + (quad << 3);
    #pragma unroll
    for (int ks = 0; ks < 16; ks++) {
        bf16x8 pa = *(const bf16x8*)&P[lm * 512 + ((((ks << 2) + quad) ^ (lm & 7)) << 3)];
        bf16x8 vf = *(const bf16x8*)(vb + (ks << 5));
        accO = __builtin_amdgcn_mfma_f32_16x16x32_bf16(pa, vf, accO, 0, 0, 0);
    }
    #pragma unroll
    for (int rg = 0; rg < 4; rg++)
        Ost[((quad << 2) + rg) * 72 + (w << 4) + lm] = f2b(accO[rg]);
    __syncthreads();
    const int r2 = t >> 4, c4 = t & 15;
    uint2 val = *(const uint2*)&Ost[r2 * 72 + (c4 << 2)];
    *(uint2*)&atted[((size_t)(b * 512 + n0 + r2)) * 768 + (h << 6) + (c4 << 2)] = val;
}

// ---------------------------------------------------------------------------
extern "C" void kernel_launch(void* const* d_in, const int* in_sizes, int n_in,
                              void* d_out, int out_size, void* d_ws, size_t ws_size,
                              hipStream_t stream)
{
    const void* v  = d_in[0];
    const void* k  = d_in[1];
    const void* q  = d_in[2];
    const void* mk = d_in[3];
    const void* Wv = d_in[6];
    const void* bv = d_in[7];
    const void* Wk = d_in[8];
    const void* bk = d_in[9];
    const void* Wq = d_in[10];
    const void* bq = d_in[11];
    const void* Wm = d_in[12];
    const void* bm = d_in[13];
    const void* pool_w = d_in[14];
    const void* pool_b = d_in[15];
    const void* w1 = d_in[16];
    const void* w2 = d_in[17];
    const void* b2 = d_in[18];

    char* ws = (char*)d_ws;
    int*   flags  = (int*)ws;                                   // 64 B
    float* alphas = (float*)(ws + 256);
    float* scores = (float*)(ws + 512);                         // 16 KB
    float* scs    = (float*)(ws + 16896);                       // 16 KB
    float* ppart  = (float*)(ws + 33280);                       // 196 KB
    float* plog   = (float*)(ws + 229888);                      // 1.2 KB
    unsigned int* pm = (unsigned int*)(ws + 262144);            // 786 KB
    unsigned short* qh  = (unsigned short*)(ws + 1048576);      // 6.29 MB each
    unsigned short* kh  = (unsigned short*)(ws + 1048576 + 1 * 6291456L);
    unsigned short* vT  = (unsigned short*)(ws + 1048576 + 2 * 6291456L);
    unsigned short* vb  = (unsigned short*)(ws + 1048576 + 3 * 6291456L);
    unsigned short* kb  = (unsigned short*)(ws + 1048576 + 4 * 6291456L);
    unsigned short* qb  = (unsigned short*)(ws + 1048576 + 5 * 6291456L);
    unsigned short* atted = kb;  // alias: kb dead by attention time (vb feeds routing)
    char* wt0 = ws + 1048576 + 6 * 6291456L;                    // 1.18 MB each
    unsigned short* WTv = (unsigned short*)(wt0);
    unsigned short* WTk = (unsigned short*)(wt0 + 1 * 1179648L);
    unsigned short* WTq = (unsigned short*)(wt0 + 2 * 1179648L);
    unsigned short* WTm = (unsigned short*)(wt0 + 3 * 1179648L);

    sniff_kernel<<<dim3(1), dim3(256), 0, stream>>>(
        (const unsigned int*)mk, (const unsigned int*)v, (const unsigned int*)Wv, flags);
    conv_act_kernel<<<dim3(1536, 3), dim3(256), 0, stream>>>(v, k, q, flags, vb, kb, qb);
    conv_wt_kernel<<<dim3(144, 4), dim3(256), 0, stream>>>(
        Wv, Wk, Wq, Wm, flags, WTv, WTk, WTq, WTm);
    pack_kernel<<<dim3(384), dim3(256), 0, stream>>>(mk, flags, pm);
    route_score_kernel<<<dim3(64), dim3(256), 0, stream>>>(vb, pool_w, pool_b, flags, scores);
    route_softmax_kernel<<<dim3(8), dim3(512), 0, stream>>>(scores, scs);
    route_pool_kernel<<<dim3(8, 8), dim3(256), 0, stream>>>(vb, flags, scs, ppart);
    route_hid_kernel<<<dim3(12, 8), dim3(256), 0, stream>>>(w1, w2, flags, ppart, plog);
    route_alpha_kernel<<<dim3(8), dim3(64), 0, stream>>>(b2, flags, plog, alphas);
    gemm3_kernel<<<dim3(768, 3), dim3(256), 0, stream>>>(
        vb, kb, qb, WTv, WTk, WTq, bv, bk, bq, flags,
        (void*)vT, (void*)kh, (void*)qh, 2, 0, 0);
    attn_kernel<<<dim3(3072), dim3(256), 0, stream>>>(qh, kh, vT, pm, alphas, atted);
    gemm3_kernel<<<dim3(768, 1), dim3(256), 0, stream>>>(
        atted, atted, atted, WTm, WTm, WTm, bm, bm, bm, flags,
        d_out, d_out, d_out, 1, 1, 1);
}